// Round 12
// baseline (198.401 us; speedup 1.0000x reference)
//
#include <hip/hip_runtime.h>
#include <hip/hip_bf16.h>
#include <stdint.h>

#define NSK 1000
#define TT  200
#define BB  64
#define NROW (BB * TT)      // 12800
#define CH  8               // scan chunk (steps)
#define RW  8               // Mv rows per scan wave (8 waves x 8 = 64)

__device__ __forceinline__ float lane_bcast(float v, int l) {
  return __uint_as_float(__builtin_amdgcn_readlane(__float_as_uint(v), l));
}
__device__ __forceinline__ unsigned ulane_bcast(unsigned v, int l) {
  return __builtin_amdgcn_readlane(v, l);
}
__device__ __forceinline__ float frcp(float x) { return __builtin_amdgcn_rcpf(x); }
__device__ __forceinline__ float sigm(float x) { return frcp(1.f + __expf(-x)); }
__device__ __forceinline__ float tanh_fast(float x) {
  return fmaf(-2.f, frcp(1.f + __expf(2.f * x)), 1.f);   // 1 - 2/(1+e^2x)
}

typedef _Float16 half2v __attribute__((ext_vector_type(2)));
union H2U { unsigned u; half2v h; };
__device__ __forceinline__ unsigned pack2h(float a, float b) {
  H2U x; x.h = (half2v){(_Float16)a, (_Float16)b}; return x.u;
}
__device__ __forceinline__ float dot2h(unsigned sp, unsigned wp, float acc) {
#if __has_builtin(__builtin_amdgcn_fdot2)
  H2U s, w; s.u = sp; w.u = wp;
  return __builtin_amdgcn_fdot2(s.h, w.h, acc, false);
#else
  H2U s, w; s.u = sp; w.u = wp;
  return fmaf((float)s.h.y, (float)w.h.y, fmaf((float)s.h.x, (float)w.h.x, acc));
#endif
}
__device__ __forceinline__ unsigned pack_pairs(float v) {
  const int lane = threadIdx.x & 63;
  float a = __shfl(v, 2 * lane);       // lanes 0..31 cover all 32 pairs
  float b = __shfl(v, 2 * lane + 1);
  return pack2h(a, b);
}

// ============ Pass A (R9-proven): 1600 blocks x 256 thr, 2 rows/wave ============
__global__ __launch_bounds__(256) void wea_kernel(
    const int* __restrict__ skills, const int* __restrict__ responses,
    const float* __restrict__ k_emb, const float* __restrict__ v_emb,
    const float* __restrict__ Mk, const float* __restrict__ eW,
    const float* __restrict__ eb, const float* __restrict__ aW,
    const float* __restrict__ ab,
    float* __restrict__ w_ws, float* __restrict__ e_ws, float* __restrict__ a_ws)
{
  __shared__ unsigned sw[3 * 64 * 40];               // 30720 B
  const int tid = threadIdx.x;
  for (int ch = tid; ch < 1536; ch += 256) {         // f16-pack Mk/eW/aW, stride 40
    const int mat = ch >> 9, rem = ch & 511;
    const int j = rem >> 3, cc = rem & 7;
    const float4* src = (mat == 0) ? (const float4*)Mk
                      : (mat == 1) ? (const float4*)eW : (const float4*)aW;
    const float4 f0 = src[j * 16 + cc * 2];
    const float4 f1 = src[j * 16 + cc * 2 + 1];
    uint4 pk;
    pk.x = pack2h(f0.x, f0.y); pk.y = pack2h(f0.z, f0.w);
    pk.z = pack2h(f1.x, f1.y); pk.w = pack2h(f1.z, f1.w);
    *(uint4*)&sw[mat * 2560 + j * 40 + ((cc + j) & 7) * 4] = pk;
  }
  __syncthreads();

  const int wave = tid >> 6, lane = tid & 63;
  const float ebl = eb[lane], abl = ab[lane];
  const int r0 = (blockIdx.x * 4 + wave) * 2;        // 1600*4*2 = 12800 exact

  float kv[2], vv[2];
  #pragma unroll
  for (int i = 0; i < 2; ++i) {
    const int sk = skills[r0 + i];
    int rr = responses[r0 + i]; rr = (rr > -1) ? rr : 0;   // masked_r
    kv[i] = k_emb[(size_t)sk * 64 + lane];
    vv[i] = v_emb[(size_t)(sk + NSK * rr) * 64 + lane];
  }
  unsigned kp[2], vp[2];
  #pragma unroll
  for (int i = 0; i < 2; ++i) { kp[i] = pack_pairs(kv[i]); vp[i] = pack_pairs(vv[i]); }

  float accK[2] = {0.f, 0.f}, accE[2] = {0.f, 0.f}, accA[2] = {0.f, 0.f};
  #pragma unroll 1
  for (int h = 0; h < 2; ++h) {
    uint4 qm[4], qe[4], qa[4];
    #pragma unroll
    for (int c = 0; c < 4; ++c) {
      const int off = lane * 40 + (((h * 4 + c) + lane) & 7) * 4;
      qm[c] = *(const uint4*)&sw[off];
      qe[c] = *(const uint4*)&sw[2560 + off];
      qa[c] = *(const uint4*)&sw[5120 + off];
    }
    #pragma unroll
    for (int i = 0; i < 2; ++i) {
      #pragma unroll
      for (int c = 0; c < 4; ++c) {
        const unsigned um[4] = {qm[c].x, qm[c].y, qm[c].z, qm[c].w};
        const unsigned ue[4] = {qe[c].x, qe[c].y, qe[c].z, qe[c].w};
        const unsigned ua[4] = {qa[c].x, qa[c].y, qa[c].z, qa[c].w};
        #pragma unroll
        for (int m = 0; m < 4; ++m) {
          const int idx = (h * 4 + c) * 4 + m;       // pair index 0..31
          const unsigned spk = ulane_bcast(kp[i], idx);
          const unsigned spv = ulane_bcast(vp[i], idx);
          accK[i] = dot2h(spk, um[m], accK[i]);
          accE[i] = dot2h(spv, ue[m], accE[i]);
          accA[i] = dot2h(spv, ua[m], accA[i]);
        }
      }
    }
  }
  #pragma unroll
  for (int i = 0; i < 2; ++i) {
    const int row = r0 + i;
    float mx = accK[i];
    #pragma unroll
    for (int off = 32; off; off >>= 1) mx = fmaxf(mx, __shfl_xor(mx, off));
    float ex = __expf(accK[i] - mx);
    float sm = ex;
    #pragma unroll
    for (int off = 32; off; off >>= 1) sm += __shfl_xor(sm, off);
    w_ws[(size_t)row * 64 + lane] = ex * frcp(sm);
    e_ws[(size_t)row * 64 + lane] = sigm(accE[i] + ebl);
    a_ws[(size_t)row * 64 + lane] = tanh_fast(accA[i] + abl);
  }
}

// ---- scan helpers ----
__device__ __forceinline__ void load_chunk(
    const float* __restrict__ wr, const float* __restrict__ er,
    const float* __restrict__ ar, int t0, int wl, int lane,
    float* wb, float* ebf, float* abf)
{
  #pragma unroll
  for (int k = 0; k < CH; ++k) {
    wb[k]  = wr[(t0 + k) * 64 + wl];
    ebf[k] = er[(t0 + k) * 64 + lane];
    abf[k] = ar[(t0 + k) * 64 + lane];
  }
}

__device__ __forceinline__ void compute_chunk(
    float* Mv, const float* wb, const float* ebf, const float* abf,
    float* __restrict__ red, int wave, int lane)
{
  #pragma unroll
  for (int k = 0; k < CH; ++k) {
    const float wv = wb[k], ev = ebf[k], av = abf[k];
    float rp = 0.f;
    #pragma unroll
    for (int i = 0; i < RW; ++i) {
      float wm = lane_bcast(wv, i);        // w[m0+i] sits in lane i (0..7)
      rp = fmaf(wm, Mv[i], rp);            // read uses PRE-update Mv
      float tp = fmaf(-ev, Mv[i], av);     // a - e*Mv
      Mv[i] = fmaf(wm, tp, Mv[i]);         // Mv += w*(a - e*Mv)
    }
    red[k * 512 + wave * 64 + lane] = rp;  // per-wave partial -> LDS
  }
}

// ============ Pass B+C fused: 64 blocks x 512 thr (8 waves) ============
// Scan: wave w owns Mv rows [8w,8w+8); per chunk ONE barrier; wave w reduces step w.
// read_ws written coalesced (stays L2-warm). fp phase: 25 outputs/wave, fW from LDS.
__global__ __launch_bounds__(512) void sfp_kernel(
    const int* __restrict__ skills, const float* __restrict__ k_emb,
    const float* __restrict__ Mv0,
    const float* __restrict__ fW, const float* __restrict__ fb,
    const float* __restrict__ pW, const float* __restrict__ pb,
    const float* __restrict__ w_ws, const float* __restrict__ e_ws,
    const float* __restrict__ a_ws,
    float* __restrict__ read_ws, float* __restrict__ out)
{
  __shared__ float sred[2][CH * 512];                // 32 KB
  __shared__ unsigned sfw[64 * 72];                  // 18432 B
  const int tid = threadIdx.x;
  const int wave = tid >> 6, lane = tid & 63;
  const int b = blockIdx.x, base = b * TT;

  // stage fW (f16 pairs, stride 72) -- region disjoint from sred
  for (int ch = tid; ch < 1024; ch += 512) {
    const int j = ch >> 4, cc = ch & 15;
    const float4 f0 = ((const float4*)fW)[j * 32 + cc * 2];
    const float4 f1 = ((const float4*)fW)[j * 32 + cc * 2 + 1];
    uint4 pk;
    pk.x = pack2h(f0.x, f0.y); pk.y = pack2h(f0.z, f0.w);
    pk.z = pack2h(f1.x, f1.y); pk.w = pack2h(f1.z, f1.w);
    *(uint4*)&sfw[j * 72 + ((cc + j) & 15) * 4] = pk;
  }

  // ---- scan ----
  const int m0 = wave * RW;
  const int wl = m0 + (lane & (RW - 1));
  float Mv[RW];
  #pragma unroll
  for (int i = 0; i < RW; ++i) Mv[i] = Mv0[(size_t)(m0 + i) * 64 + lane];
  const float* wr = w_ws + (size_t)base * 64;
  const float* er = e_ws + (size_t)base * 64;
  const float* ar = a_ws + (size_t)base * 64;

  float wb0[CH], eb0[CH], ab0[CH];
  float wb1[CH], eb1[CH], ab1[CH];
  load_chunk(wr, er, ar, 0, wl, lane, wb0, eb0, ab0);
  __syncthreads();                                   // fW staged

  for (int c = 0; c < TT / CH; ++c) {                // 25 chunks, 1 barrier each
    if (c + 1 < TT / CH) {                           // prefetch into buffer (c+1)&1
      if (c & 1) load_chunk(wr, er, ar, (c + 1) * CH, wl, lane, wb0, eb0, ab0);
      else       load_chunk(wr, er, ar, (c + 1) * CH, wl, lane, wb1, eb1, ab1);
    }
    float* red = sred[c & 1];
    if (c & 1) compute_chunk(Mv, wb1, eb1, ab1, red, wave, lane);
    else       compute_chunk(Mv, wb0, eb0, ab0, red, wave, lane);
    __syncthreads();                                 // compute(c) done; red[(c)&1] free
                                                     // for compute(c+2) after next bar
    const float* r = red + wave * 512;               // wave reduces step k = wave
    float v = ((r[0 * 64 + lane] + r[1 * 64 + lane]) + (r[2 * 64 + lane] + r[3 * 64 + lane]))
            + ((r[4 * 64 + lane] + r[5 * 64 + lane]) + (r[6 * 64 + lane] + r[7 * 64 + lane]));
    read_ws[(size_t)(base + c * CH + wave) * 64 + lane] = v;
  }
  __threadfence_block();
  __syncthreads();                                   // all read_ws visible in-block

  // ---- fp: wave w -> outputs o = w*25 .. w*25+24 (o < 199) ----
  const float fbl = fb[lane], pwl = pW[lane], pb0 = pb[0];
  #pragma unroll 1
  for (int g0 = 0; g0 < 25; g0 += 5) {
    float rv[5], kc[5];
    int ov[5];
    #pragma unroll
    for (int i = 0; i < 5; ++i) {
      const int o = wave * 25 + g0 + i;
      ov[i] = o;
      const int t = (o < TT - 1) ? o + 1 : TT - 1;
      rv[i] = read_ws[(size_t)(base + t) * 64 + lane];
      kc[i] = k_emb[(size_t)skills[base + t] * 64 + lane];
    }
    unsigned rvp[5], kvp[5];
    #pragma unroll
    for (int i = 0; i < 5; ++i) { rvp[i] = pack_pairs(rv[i]); kvp[i] = pack_pairs(kc[i]); }

    float acc[5] = {fbl, fbl, fbl, fbl, fbl};
    #pragma unroll 1
    for (int h = 0; h < 4; ++h) {                    // quarters: 4 uint4 (32 inputs)
      uint4 qf[4];
      #pragma unroll
      for (int c = 0; c < 4; ++c)
        qf[c] = *(const uint4*)&sfw[lane * 72 + (((h * 4 + c) + lane) & 15) * 4];
      #pragma unroll
      for (int i = 0; i < 5; ++i) {
        #pragma unroll
        for (int c = 0; c < 4; ++c) {
          const unsigned uu[4] = {qf[c].x, qf[c].y, qf[c].z, qf[c].w};
          #pragma unroll
          for (int m = 0; m < 4; ++m) {
            const int idx = (h * 4 + c) * 4 + m;     // pair index 0..63
            const unsigned sp = (idx < 32) ? ulane_bcast(rvp[i], idx)
                                           : ulane_bcast(kvp[i], idx - 32);
            acc[i] = dot2h(sp, uu[m], acc[i]);
          }
        }
      }
    }
    #pragma unroll
    for (int i = 0; i < 5; ++i) {
      float f = tanh_fast(acc[i]) * pwl;
      #pragma unroll
      for (int off = 32; off; off >>= 1) f += __shfl_xor(f, off);
      if (lane == 0 && ov[i] < TT - 1)
        out[(size_t)b * (TT - 1) + ov[i]] = sigm(f + pb0);
    }
  }
}

extern "C" void kernel_launch(void* const* d_in, const int* in_sizes, int n_in,
                              void* d_out, int out_size, void* d_ws, size_t ws_size,
                              hipStream_t stream) {
  const int* skills    = (const int*)d_in[0];
  const int* responses = (const int*)d_in[1];
  const float* k_emb   = (const float*)d_in[2];
  const float* v_emb   = (const float*)d_in[3];
  const float* Mk      = (const float*)d_in[4];
  const float* Mv0     = (const float*)d_in[5];
  const float* fW      = (const float*)d_in[6];
  const float* fb      = (const float*)d_in[7];
  const float* eW      = (const float*)d_in[8];
  const float* eb      = (const float*)d_in[9];
  const float* aW      = (const float*)d_in[10];
  const float* ab      = (const float*)d_in[11];
  const float* pW      = (const float*)d_in[12];
  const float* pb      = (const float*)d_in[13];

  // fp32 scratch: w | e | a | read (B*T*64 each) ~= 13.1 MB; no counters, no memset
  float* w_ws    = (float*)d_ws;
  float* e_ws    = w_ws + (size_t)BB * TT * 64;
  float* a_ws    = e_ws + (size_t)BB * TT * 64;
  float* read_ws = a_ws + (size_t)BB * TT * 64;

  wea_kernel<<<dim3(NROW / 8), 256, 0, stream>>>(
      skills, responses, k_emb, v_emb, Mk, eW, eb, aW, ab, w_ws, e_ws, a_ws);
  sfp_kernel<<<dim3(BB), 512, 0, stream>>>(
      skills, k_emb, Mv0, fW, fb, pW, pb, w_ws, e_ws, a_ws,
      read_ws, (float*)d_out);
}

// Round 13
// 128.655 us; speedup vs baseline: 1.5421x; 1.5421x over previous
//
#include <hip/hip_runtime.h>
#include <hip/hip_bf16.h>
#include <stdint.h>

#define NSK 1000
#define TT  200
#define BB  64
#define NROW (BB * TT)      // 12800
#define NOUT (BB * (TT-1))  // 12736
#define CH  20              // scan pipeline depth (steps); TT/CH = 10 chunks (even)
#define RW  8               // scan Mv rows per wave

__device__ __forceinline__ float lane_bcast(float v, int l) {
  return __uint_as_float(__builtin_amdgcn_readlane(__float_as_uint(v), l));
}
__device__ __forceinline__ unsigned ulane_bcast(unsigned v, int l) {
  return __builtin_amdgcn_readlane(v, l);
}
__device__ __forceinline__ float frcp(float x) { return __builtin_amdgcn_rcpf(x); }
__device__ __forceinline__ float sigm(float x) { return frcp(1.f + __expf(-x)); }
__device__ __forceinline__ float tanh_fast(float x) {
  return fmaf(-2.f, frcp(1.f + __expf(2.f * x)), 1.f);   // 1 - 2/(1+e^2x)
}

typedef _Float16 half2v __attribute__((ext_vector_type(2)));
union H2U { unsigned u; half2v h; };
__device__ __forceinline__ unsigned pack2h(float a, float b) {
  H2U x; x.h = (half2v){(_Float16)a, (_Float16)b}; return x.u;
}
__device__ __forceinline__ unsigned short f16bits(float x) {
  H2U u; u.h = (half2v){(_Float16)x, (_Float16)0.f}; return (unsigned short)(u.u & 0xffffu);
}
__device__ __forceinline__ float f16lo(unsigned bits) {
  H2U u; u.u = bits; return (float)u.h.x;
}
__device__ __forceinline__ float f16hi(unsigned bits) {
  H2U u; u.u = bits; return (float)u.h.y;
}
__device__ __forceinline__ float dot2h(unsigned sp, unsigned wp, float acc) {
#if __has_builtin(__builtin_amdgcn_fdot2)
  H2U s, w; s.u = sp; w.u = wp;
  return __builtin_amdgcn_fdot2(s.h, w.h, acc, false);
#else
  H2U s, w; s.u = sp; w.u = wp;
  return fmaf((float)s.h.y, (float)w.h.y, fmaf((float)s.h.x, (float)w.h.x, acc));
#endif
}
__device__ __forceinline__ unsigned pack_pairs(float v) {
  const int lane = threadIdx.x & 63;
  float a = __shfl(v, 2 * lane);       // lanes 0..31 cover all 32 pairs
  float b = __shfl(v, 2 * lane + 1);
  return pack2h(a, b);
}

// ============ Pass A (R9 structure): 1600 blocks x 256 thr, 2 rows/wave ============
// Outputs f16-packed: ea_ws[row*64+lane] = (e,a) pair; w16_ws[row*64+lane] = w.
__global__ __launch_bounds__(256) void wea_kernel(
    const int* __restrict__ skills, const int* __restrict__ responses,
    const float* __restrict__ k_emb, const float* __restrict__ v_emb,
    const float* __restrict__ Mk, const float* __restrict__ eW,
    const float* __restrict__ eb, const float* __restrict__ aW,
    const float* __restrict__ ab,
    unsigned* __restrict__ ea_ws, unsigned short* __restrict__ w16_ws)
{
  __shared__ unsigned sw[3 * 64 * 40];               // 30720 B
  const int tid = threadIdx.x;
  for (int ch = tid; ch < 1536; ch += 256) {         // f16-pack Mk/eW/aW, stride 40
    const int mat = ch >> 9, rem = ch & 511;
    const int j = rem >> 3, cc = rem & 7;
    const float4* src = (mat == 0) ? (const float4*)Mk
                      : (mat == 1) ? (const float4*)eW : (const float4*)aW;
    const float4 f0 = src[j * 16 + cc * 2];
    const float4 f1 = src[j * 16 + cc * 2 + 1];
    uint4 pk;
    pk.x = pack2h(f0.x, f0.y); pk.y = pack2h(f0.z, f0.w);
    pk.z = pack2h(f1.x, f1.y); pk.w = pack2h(f1.z, f1.w);
    *(uint4*)&sw[mat * 2560 + j * 40 + ((cc + j) & 7) * 4] = pk;
  }
  __syncthreads();

  const int wave = tid >> 6, lane = tid & 63;
  const float ebl = eb[lane], abl = ab[lane];
  const int r0 = (blockIdx.x * 4 + wave) * 2;        // 1600*4*2 = 12800 exact

  float kv[2], vv[2];
  #pragma unroll
  for (int i = 0; i < 2; ++i) {
    const int sk = skills[r0 + i];
    int rr = responses[r0 + i]; rr = (rr > -1) ? rr : 0;   // masked_r
    kv[i] = k_emb[(size_t)sk * 64 + lane];
    vv[i] = v_emb[(size_t)(sk + NSK * rr) * 64 + lane];
  }
  unsigned kp[2], vp[2];
  #pragma unroll
  for (int i = 0; i < 2; ++i) { kp[i] = pack_pairs(kv[i]); vp[i] = pack_pairs(vv[i]); }

  float accK[2] = {0.f, 0.f}, accE[2] = {0.f, 0.f}, accA[2] = {0.f, 0.f};
  #pragma unroll 1
  for (int h = 0; h < 2; ++h) {
    uint4 qm[4], qe[4], qa[4];
    #pragma unroll
    for (int c = 0; c < 4; ++c) {
      const int off = lane * 40 + (((h * 4 + c) + lane) & 7) * 4;
      qm[c] = *(const uint4*)&sw[off];
      qe[c] = *(const uint4*)&sw[2560 + off];
      qa[c] = *(const uint4*)&sw[5120 + off];
    }
    #pragma unroll
    for (int i = 0; i < 2; ++i) {
      #pragma unroll
      for (int c = 0; c < 4; ++c) {
        const unsigned um[4] = {qm[c].x, qm[c].y, qm[c].z, qm[c].w};
        const unsigned ue[4] = {qe[c].x, qe[c].y, qe[c].z, qe[c].w};
        const unsigned ua[4] = {qa[c].x, qa[c].y, qa[c].z, qa[c].w};
        #pragma unroll
        for (int m = 0; m < 4; ++m) {
          const int idx = (h * 4 + c) * 4 + m;       // pair index 0..31
          const unsigned spk = ulane_bcast(kp[i], idx);
          const unsigned spv = ulane_bcast(vp[i], idx);
          accK[i] = dot2h(spk, um[m], accK[i]);
          accE[i] = dot2h(spv, ue[m], accE[i]);
          accA[i] = dot2h(spv, ua[m], accA[i]);
        }
      }
    }
  }
  #pragma unroll
  for (int i = 0; i < 2; ++i) {
    const int row = r0 + i;
    float mx = accK[i];
    #pragma unroll
    for (int off = 32; off; off >>= 1) mx = fmaxf(mx, __shfl_xor(mx, off));
    float ex = __expf(accK[i] - mx);
    float sm = ex;
    #pragma unroll
    for (int off = 32; off; off >>= 1) sm += __shfl_xor(sm, off);
    const float wv  = ex * frcp(sm);
    const float evv = sigm(accE[i] + ebl);
    const float avv = tanh_fast(accA[i] + abl);
    ea_ws[(size_t)row * 64 + lane]  = pack2h(evv, avv);
    w16_ws[(size_t)row * 64 + lane] = f16bits(wv);
  }
}

// ---- scan helpers (f16-packed inputs, CH=20) ----
__device__ __forceinline__ void load_chunk(
    const unsigned* __restrict__ eap, const unsigned short* __restrict__ wp,
    int t0, int wl, int lane, unsigned* eab, unsigned* wvb)
{
  #pragma unroll
  for (int k = 0; k < CH; ++k) {
    eab[k] = eap[(t0 + k) * 64 + lane];
    wvb[k] = (unsigned)wp[(t0 + k) * 64 + wl];
  }
}

__device__ __forceinline__ void compute_chunk(
    float* Mv, const unsigned* eab, const unsigned* wvb,
    float* __restrict__ red, int wave, int lane)
{
  #pragma unroll
  for (int k = 0; k < CH; ++k) {
    const float ev = f16lo(eab[k]), av = f16hi(eab[k]);
    float rp = 0.f;
    #pragma unroll
    for (int i = 0; i < RW; ++i) {
      const float wm = f16lo(ulane_bcast(wvb[k], i));  // w[m0+i] sits in lane i (0..7)
      rp = fmaf(wm, Mv[i], rp);            // read uses PRE-update Mv
      float tp = fmaf(-ev, Mv[i], av);     // a - e*Mv
      Mv[i] = fmaf(wm, tp, Mv[i]);         // Mv += w*(a - e*Mv)
    }
    red[k * 256 + wave * 64 + lane] = rp;  // per-wave partial -> LDS
  }
}

// in-block reduce: wave w sums steps w*5..w*5+4 of the chunk -> f16 partial
__device__ __forceinline__ void reduce_store(
    const float* __restrict__ red, int ch, int base, int wave, int lane,
    unsigned short* __restrict__ ps)
{
  #pragma unroll
  for (int u = 0; u < 5; ++u) {
    const int k = wave * 5 + u;
    const float* rr = red + k * 256;
    const float v = (rr[lane] + rr[64 + lane]) + (rr[128 + lane] + rr[192 + lane]);
    ps[(size_t)(base + ch * CH + k) * 64 + lane] = f16bits(v);
  }
}

// ============ Pass B (R9 structure): 128 blocks x 256 thr, 2 blocks/batch ============
__global__ __launch_bounds__(256) void scan_kernel(
    const float* __restrict__ Mv0,
    const unsigned* __restrict__ ea_ws, const unsigned short* __restrict__ w16_ws,
    unsigned short* __restrict__ p0, unsigned short* __restrict__ p1)
{
  __shared__ float red[2][CH * 256];                 // 40 KB
  const int b    = blockIdx.x >> 1;
  const int s    = blockIdx.x & 1;
  const int wave = threadIdx.x >> 6;
  const int lane = threadIdx.x & 63;
  const int base = b * TT;
  const int m0   = s * 32 + wave * RW;
  const int wl   = m0 + (lane & (RW - 1));
  unsigned short* ps = s ? p1 : p0;

  float Mv[RW];
  #pragma unroll
  for (int i = 0; i < RW; ++i) Mv[i] = Mv0[(size_t)(m0 + i) * 64 + lane];

  const unsigned* eap = ea_ws + (size_t)base * 64;
  const unsigned short* wp = w16_ws + (size_t)base * 64;

  unsigned ea0[CH], wv0[CH], ea1[CH], wv1[CH];
  load_chunk(eap, wp, 0, wl, lane, ea0, wv0);
  for (int ch = 0; ch < TT / CH; ch += 2) {          // 10 chunks
    if ((ch + 1) * CH < TT)
      load_chunk(eap, wp, (ch + 1) * CH, wl, lane, ea1, wv1);
    compute_chunk(Mv, ea0, wv0, red[0], wave, lane);
    __syncthreads();
    reduce_store(red[0], ch, base, wave, lane, ps);
    if ((ch + 2) * CH < TT)
      load_chunk(eap, wp, (ch + 2) * CH, wl, lane, ea0, wv0);
    if ((ch + 1) * CH < TT) {
      compute_chunk(Mv, ea1, wv1, red[1], wave, lane);
      __syncthreads();
      reduce_store(red[1], ch + 1, base, wave, lane, ps);
    }
  }
}

// ============ Pass C (R9 structure): 1592 blocks x 256 thr, 2 outputs/wave ============
__global__ __launch_bounds__(256) void fp_kernel(
    const int* __restrict__ skills, const float* __restrict__ k_emb,
    const float* __restrict__ fW, const float* __restrict__ fb,
    const float* __restrict__ pW, const float* __restrict__ pb,
    const unsigned short* __restrict__ p0, const unsigned short* __restrict__ p1,
    float* __restrict__ out)
{
  __shared__ unsigned sf[64 * 72];                   // 18432 B
  const int tid = threadIdx.x;
  for (int ch = tid; ch < 1024; ch += 256) {         // f16-pack fW, stride 72
    const int j = ch >> 4, cc = ch & 15;
    const float4 f0 = ((const float4*)fW)[j * 32 + cc * 2];
    const float4 f1 = ((const float4*)fW)[j * 32 + cc * 2 + 1];
    uint4 pk;
    pk.x = pack2h(f0.x, f0.y); pk.y = pack2h(f0.z, f0.w);
    pk.z = pack2h(f1.x, f1.y); pk.w = pack2h(f1.z, f1.w);
    *(uint4*)&sf[j * 72 + ((cc + j) & 15) * 4] = pk;
  }
  __syncthreads();

  const int wave = tid >> 6, lane = tid & 63;
  const float fbl = fb[lane], pwl = pW[lane], pb0 = pb[0];
  const int p = blockIdx.x * 4 + wave;               // pair id, 1592*4 = 6368 exact

  float rv[2], kc[2];
  int bsave[2], tsave[2];
  #pragma unroll
  for (int i = 0; i < 2; ++i) {
    const unsigned idx = 2u * p + i;
    const unsigned b = idx / 199u;
    const int row = (int)(idx + b + 1u);
    bsave[i] = (int)b; tsave[i] = (int)(idx - b * 199u);
    rv[i] = f16lo((unsigned)p0[(size_t)row * 64 + lane])
          + f16lo((unsigned)p1[(size_t)row * 64 + lane]);
    kc[i] = k_emb[(size_t)skills[row] * 64 + lane];
  }
  unsigned rvp[2], kvp[2];
  #pragma unroll
  for (int i = 0; i < 2; ++i) {
    rvp[i] = pack_pairs(rv[i]);
    kvp[i] = pack_pairs(kc[i]);
  }

  float acc[2] = {fbl, fbl};
  #pragma unroll 1
  for (int h = 0; h < 4; ++h) {                      // quarters: 4 uint4 (32 inputs)
    uint4 qf[4];
    #pragma unroll
    for (int c = 0; c < 4; ++c)
      qf[c] = *(const uint4*)&sf[lane * 72 + (((h * 4 + c) + lane) & 15) * 4];
    #pragma unroll
    for (int i = 0; i < 2; ++i) {
      #pragma unroll
      for (int c = 0; c < 4; ++c) {
        const unsigned uu[4] = {qf[c].x, qf[c].y, qf[c].z, qf[c].w};
        #pragma unroll
        for (int m = 0; m < 4; ++m) {
          const int idx = (h * 4 + c) * 4 + m;       // pair index 0..63
          const unsigned sp = (idx < 32) ? ulane_bcast(rvp[i], idx)
                                         : ulane_bcast(kvp[i], idx - 32);
          acc[i] = dot2h(sp, uu[m], acc[i]);
        }
      }
    }
  }

  float f0 = tanh_fast(acc[0]) * pwl;
  float f1 = tanh_fast(acc[1]) * pwl;
  #pragma unroll
  for (int off = 32; off; off >>= 1) {
    f0 += __shfl_xor(f0, off);
    f1 += __shfl_xor(f1, off);
  }
  if (lane == 0) {
    out[(size_t)bsave[0] * (TT - 1) + tsave[0]] = sigm(f0 + pb0);
    out[(size_t)bsave[1] * (TT - 1) + tsave[1]] = sigm(f1 + pb0);
  }
}

extern "C" void kernel_launch(void* const* d_in, const int* in_sizes, int n_in,
                              void* d_out, int out_size, void* d_ws, size_t ws_size,
                              hipStream_t stream) {
  const int* skills    = (const int*)d_in[0];
  const int* responses = (const int*)d_in[1];
  const float* k_emb   = (const float*)d_in[2];
  const float* v_emb   = (const float*)d_in[3];
  const float* Mk      = (const float*)d_in[4];
  const float* Mv0     = (const float*)d_in[5];
  const float* fW      = (const float*)d_in[6];
  const float* fb      = (const float*)d_in[7];
  const float* eW      = (const float*)d_in[8];
  const float* eb      = (const float*)d_in[9];
  const float* aW      = (const float*)d_in[10];
  const float* ab      = (const float*)d_in[11];
  const float* pW      = (const float*)d_in[12];
  const float* pb      = (const float*)d_in[13];

  // f16-packed scratch: ea (dword pairs, 3.3MB) | w16 (1.6MB) | p0 | p1 (1.6MB each)
  unsigned* ea_ws       = (unsigned*)d_ws;
  unsigned short* w16_ws = (unsigned short*)(ea_ws + (size_t)NROW * 64);
  unsigned short* p0    = w16_ws + (size_t)NROW * 64;
  unsigned short* p1    = p0 + (size_t)NROW * 64;

  wea_kernel<<<dim3(NROW / 8), 256, 0, stream>>>(
      skills, responses, k_emb, v_emb, Mk, eW, eb, aW, ab, ea_ws, w16_ws);
  scan_kernel<<<dim3(BB * 2), 256, 0, stream>>>(Mv0, ea_ws, w16_ws, p0, p1);
  fp_kernel<<<dim3(NOUT / 8), 256, 0, stream>>>(
      skills, k_emb, fW, fb, pW, pb, p0, p1, (float*)d_out);
}